// Round 1
// baseline (581.786 us; speedup 1.0000x reference)
//
#include <hip/hip_runtime.h>
#include <hip/hip_bf16.h>
#include <math.h>

#define M_TOK 2048
#define DDIM  1024
#define FDIM  4096
#define NEXP  8

typedef __attribute__((ext_vector_type(8))) short short8;
typedef __attribute__((ext_vector_type(4))) float f32x4;
typedef unsigned short ushort_t;

// ---------- helpers ----------
__device__ inline unsigned short f2b(float f) {        // f32 -> bf16 RNE
  unsigned int u = __float_as_uint(f);
  u = u + 0x7FFFu + ((u >> 16) & 1u);
  return (unsigned short)(u >> 16);
}

__device__ inline float gelu_tanh(float u) {           // jax.nn.gelu approximate=True
  float u3 = u * u * u;
  float a  = 0.7978845608028654f * (u + 0.044715f * u3);
  float e  = __expf(2.0f * a);
  float t  = 1.0f - 2.0f / (e + 1.0f);                 // tanh(a), inf-safe
  return 0.5f * u * (1.0f + t);
}

__device__ inline void gload_lds16(const void* g, void* l) {
  __builtin_amdgcn_global_load_lds(
      (const __attribute__((address_space(1))) unsigned int*)g,
      (__attribute__((address_space(3))) unsigned int*)l, 16, 0, 0);
}

__device__ inline float fget(const float4& v, int j) {
  return j == 0 ? v.x : j == 1 ? v.y : j == 2 ? v.z : v.w;
}

// ---------- 0: zero out + counters ----------
__global__ void zero_kernel(float* __restrict__ out, int* __restrict__ cnt) {
  size_t i = (size_t)blockIdx.x * 256 + threadIdx.x;   // 2048 blocks * 256 = 2M float4? no: 512K float4
  float4 z = {0.f, 0.f, 0.f, 0.f};
  ((float4*)out)[i] = z;                               // 2048*256 float4 = 2M floats = out
  if (blockIdx.x == 0 && threadIdx.x < NEXP) cnt[threadIdx.x] = 0;
}

// ---------- 1: router (f64 logits, softmax, top-2, append) ----------
__global__ void router_kernel(const float* __restrict__ x, const float* __restrict__ rw,
                              int* __restrict__ cnt, int* __restrict__ tmp_tok,
                              float* __restrict__ tmp_gate) {
  int tok  = blockIdx.x * 4 + (threadIdx.x >> 6);
  int lane = threadIdx.x & 63;
  const float* xr = x + (size_t)tok * DDIM;
  double acc[NEXP];
#pragma unroll
  for (int e = 0; e < NEXP; e++) acc[e] = 0.0;
  for (int d = lane; d < DDIM; d += 64) {
    double xv = (double)xr[d];
    const float* rp = rw + (size_t)d * NEXP;
#pragma unroll
    for (int e = 0; e < NEXP; e++) acc[e] += xv * (double)rp[e];
  }
#pragma unroll
  for (int off = 32; off >= 1; off >>= 1) {
#pragma unroll
    for (int e = 0; e < NEXP; e++) acc[e] += __shfl_down(acc[e], off, 64);
  }
  if (lane == 0) {
    double mx = acc[0];
    for (int e = 1; e < NEXP; e++) mx = fmax(mx, acc[e]);
    double p[NEXP], sum = 0.0;
    for (int e = 0; e < NEXP; e++) { p[e] = exp(acc[e] - mx); sum += p[e]; }
    for (int e = 0; e < NEXP; e++) p[e] /= sum;
    int i0 = 0;
    for (int e = 1; e < NEXP; e++) if (p[e] > p[i0]) i0 = e;          // lowest idx on tie
    int i1 = (i0 == 0) ? 1 : 0;
    for (int e = 0; e < NEXP; e++) if (e != i0 && p[e] > p[i1]) i1 = e;
    int pos0 = atomicAdd(&cnt[i0], 1);
    tmp_tok[i0 * M_TOK + pos0]  = tok;
    tmp_gate[i0 * M_TOK + pos0] = (float)p[i0];
    int pos1 = atomicAdd(&cnt[i1], 1);
    tmp_tok[i1 * M_TOK + pos1]  = tok;
    tmp_gate[i1 * M_TOK + pos1] = (float)p[i1];
  }
}

// ---------- 2: offsets (pad to 128) + compact ----------
__global__ void finalize_kernel(const int* __restrict__ cnt, int* __restrict__ pofs,
                                int* __restrict__ meta, int* __restrict__ ptok,
                                float* __restrict__ pgate, const int* __restrict__ tmp_tok,
                                const float* __restrict__ tmp_gate) {
  __shared__ int ofs[NEXP];
  if (threadIdx.x == 0) {
    int o = 0;
    for (int e = 0; e < NEXP; e++) {
      ofs[e] = o; pofs[e] = o;
      o += ((cnt[e] + 127) >> 7) << 7;
    }
    meta[0] = o;
  }
  __syncthreads();
  for (int i = threadIdx.x; i < NEXP * M_TOK; i += 256) {
    int e = i >> 11, sl = i & 2047;
    int c = cnt[e];
    int padded = ((c + 127) >> 7) << 7;
    if (sl < padded) {
      int dst = ofs[e] + sl;
      if (sl < c) { ptok[dst] = tmp_tok[i]; pgate[dst] = tmp_gate[i]; }
      else        { ptok[dst] = -1;         pgate[dst] = 0.0f; }
    }
  }
}

// ---------- 3: gather x rows -> bf16 Xg ----------
__global__ void gather_kernel(const float* __restrict__ x, const int* __restrict__ ptok,
                              const int* __restrict__ meta, ushort_t* __restrict__ Xg) {
  int r = blockIdx.x;
  if (r >= meta[0]) return;
  int tok = ptok[r];
  int t = threadIdx.x;
  ushort4 b;
  if (tok >= 0) {
    float4 v = *(const float4*)(x + (size_t)tok * DDIM + t * 4);
    b.x = f2b(v.x); b.y = f2b(v.y); b.z = f2b(v.z); b.w = f2b(v.w);
  } else {
    b.x = 0; b.y = 0; b.z = 0; b.w = 0;
  }
  *(ushort4*)(Xg + (size_t)r * DDIM + t * 4) = b;
}

// ---------- 4: GEMM1 fused: v = Xg@wv*sv, y = gelu(Xg@w*s), G = v*y (bf16) ----------
__launch_bounds__(256, 2)
__global__ void gemm1_kernel(const ushort_t* __restrict__ Xg,
                             const float* __restrict__ wv, const float* __restrict__ sv,
                             const float* __restrict__ w,  const float* __restrict__ s,
                             const int* __restrict__ cnt,  const int* __restrict__ pofs,
                             ushort_t* __restrict__ G) {
  int e = blockIdx.z, rt = blockIdx.y, ct = blockIdx.x;
  int cn = cnt[e];
  if (rt * 128 >= cn) return;
  int gr0 = pofs[e] + rt * 128;

  const float* Bv = wv + (size_t)e * DDIM * FDIM + (size_t)ct * 128;
  const float* Bw = w  + (size_t)e * DDIM * FDIM + (size_t)ct * 128;

  __shared__ ushort_t As[128][32];
  __shared__ ushort_t Bs[2][128][40];   // [n][k] transposed, padded rows (80B)

  int tid = threadIdx.x;
  int wid = tid >> 6, lane = tid & 63;
  int wr = wid >> 1, wc = wid & 1;

  f32x4 accv[4][4], accy[4][4];
  f32x4 zf = {0.f, 0.f, 0.f, 0.f};
#pragma unroll
  for (int mi = 0; mi < 4; mi++)
#pragma unroll
    for (int ni = 0; ni < 4; ni++) { accv[mi][ni] = zf; accy[mi][ni] = zf; }

  int kblk = tid >> 5;          // 0..7  (4 k-rows each)
  int nb   = tid & 31;          // n-quad
  int a_lrow = lane >> 2;
  int a_lcol = (lane & 3) * 8;  // elems

  for (int kt = 0; kt < DDIM / 32; kt++) {
    __syncthreads();
    // A tile: 8 chunks of 16 rows x 64B via global_load_lds
#pragma unroll
    for (int i = 0; i < 2; i++) {
      int chunk = wid + i * 4;
      const ushort_t* src = Xg + (size_t)(gr0 + chunk * 16 + a_lrow) * DDIM + kt * 32 + a_lcol;
      gload_lds16(src, &As[chunk * 16][0]);
    }
    // B tiles: load f32, convert, transpose into LDS
    float4 qv[4], qw[4];
#pragma unroll
    for (int i = 0; i < 4; i++) {
      size_t rowk = (size_t)(kt * 32 + kblk * 4 + i);
      qv[i] = *(const float4*)(Bv + rowk * FDIM + nb * 4);
      qw[i] = *(const float4*)(Bw + rowk * FDIM + nb * 4);
    }
#pragma unroll
    for (int j = 0; j < 4; j++) {
      ushort4 pv, pw;
      pv.x = f2b(fget(qv[0], j)); pv.y = f2b(fget(qv[1], j));
      pv.z = f2b(fget(qv[2], j)); pv.w = f2b(fget(qv[3], j));
      pw.x = f2b(fget(qw[0], j)); pw.y = f2b(fget(qw[1], j));
      pw.z = f2b(fget(qw[2], j)); pw.w = f2b(fget(qw[3], j));
      *(ushort4*)&Bs[0][nb * 4 + j][kblk * 4] = pv;
      *(ushort4*)&Bs[1][nb * 4 + j][kblk * 4] = pw;
    }
    __syncthreads();

    short8 af[4], bvf[4], bwf[4];
#pragma unroll
    for (int mi = 0; mi < 4; mi++)
      af[mi] = *(const short8*)&As[wr * 64 + mi * 16 + (lane & 15)][(lane >> 4) * 8];
#pragma unroll
    for (int ni = 0; ni < 4; ni++) {
      bvf[ni] = *(const short8*)&Bs[0][wc * 64 + ni * 16 + (lane & 15)][(lane >> 4) * 8];
      bwf[ni] = *(const short8*)&Bs[1][wc * 64 + ni * 16 + (lane & 15)][(lane >> 4) * 8];
    }
#pragma unroll
    for (int mi = 0; mi < 4; mi++)
#pragma unroll
      for (int ni = 0; ni < 4; ni++) {
        accv[mi][ni] = __builtin_amdgcn_mfma_f32_16x16x32_bf16(af[mi], bvf[ni], accv[mi][ni], 0, 0, 0);
        accy[mi][ni] = __builtin_amdgcn_mfma_f32_16x16x32_bf16(af[mi], bwf[ni], accy[mi][ni], 0, 0, 0);
      }
  }

  const float* svp = sv + (size_t)e * FDIM + ct * 128;
  const float* sp  = s  + (size_t)e * FDIM + ct * 128;
#pragma unroll
  for (int ni = 0; ni < 4; ni++) {
    int coll = wc * 64 + ni * 16 + (lane & 15);
    float scv = svp[coll], scy = sp[coll];
#pragma unroll
    for (int mi = 0; mi < 4; mi++)
#pragma unroll
      for (int q = 0; q < 4; q++) {
        int rowl = wr * 64 + mi * 16 + (lane >> 4) * 4 + q;
        float vv = accv[mi][ni][q] * scv;
        float yy = accy[mi][ni][q] * scy;
        float g  = vv * gelu_tanh(yy);
        G[(size_t)(gr0 + rowl) * FDIM + ct * 128 + coll] = f2b(g);
      }
  }
}

// ---------- 5: GEMM2: out[tok] += gate * (G @ w1) * s1 ----------
__launch_bounds__(256, 2)
__global__ void gemm2_kernel(const ushort_t* __restrict__ G,
                             const float* __restrict__ w1, const float* __restrict__ s1,
                             const int* __restrict__ cnt,  const int* __restrict__ pofs,
                             const int* __restrict__ ptok, const float* __restrict__ pgate,
                             float* __restrict__ out) {
  int e = blockIdx.z, rt = blockIdx.y, ct = blockIdx.x;
  int cn = cnt[e];
  if (rt * 128 >= cn) return;
  int gr0 = pofs[e] + rt * 128;
  const float* Bp = w1 + (size_t)e * FDIM * DDIM + (size_t)ct * 128;

  __shared__ ushort_t As[128][32];
  __shared__ ushort_t Bs[128][40];

  int tid = threadIdx.x;
  int wid = tid >> 6, lane = tid & 63;
  int wr = wid >> 1, wc = wid & 1;

  f32x4 acc[4][4];
  f32x4 zf = {0.f, 0.f, 0.f, 0.f};
#pragma unroll
  for (int mi = 0; mi < 4; mi++)
#pragma unroll
    for (int ni = 0; ni < 4; ni++) acc[mi][ni] = zf;

  int kblk = tid >> 5;
  int nb   = tid & 31;
  int a_lrow = lane >> 2;
  int a_lcol = (lane & 3) * 8;

  for (int kt = 0; kt < FDIM / 32; kt++) {
    __syncthreads();
#pragma unroll
    for (int i = 0; i < 2; i++) {
      int chunk = wid + i * 4;
      const ushort_t* src = G + (size_t)(gr0 + chunk * 16 + a_lrow) * FDIM + kt * 32 + a_lcol;
      gload_lds16(src, &As[chunk * 16][0]);
    }
    float4 q[4];
#pragma unroll
    for (int i = 0; i < 4; i++) {
      size_t rowk = (size_t)(kt * 32 + kblk * 4 + i);
      q[i] = *(const float4*)(Bp + rowk * DDIM + nb * 4);
    }
#pragma unroll
    for (int j = 0; j < 4; j++) {
      ushort4 pq;
      pq.x = f2b(fget(q[0], j)); pq.y = f2b(fget(q[1], j));
      pq.z = f2b(fget(q[2], j)); pq.w = f2b(fget(q[3], j));
      *(ushort4*)&Bs[nb * 4 + j][kblk * 4] = pq;
    }
    __syncthreads();

    short8 af[4], bf[4];
#pragma unroll
    for (int mi = 0; mi < 4; mi++)
      af[mi] = *(const short8*)&As[wr * 64 + mi * 16 + (lane & 15)][(lane >> 4) * 8];
#pragma unroll
    for (int ni = 0; ni < 4; ni++)
      bf[ni] = *(const short8*)&Bs[wc * 64 + ni * 16 + (lane & 15)][(lane >> 4) * 8];
#pragma unroll
    for (int mi = 0; mi < 4; mi++)
#pragma unroll
      for (int ni = 0; ni < 4; ni++)
        acc[mi][ni] = __builtin_amdgcn_mfma_f32_16x16x32_bf16(af[mi], bf[ni], acc[mi][ni], 0, 0, 0);
  }

  const float* s1p = s1 + (size_t)e * DDIM + ct * 128;
#pragma unroll
  for (int ni = 0; ni < 4; ni++) {
    int coll = wc * 64 + ni * 16 + (lane & 15);
    float sc = s1p[coll];
#pragma unroll
    for (int mi = 0; mi < 4; mi++)
#pragma unroll
      for (int q = 0; q < 4; q++) {
        int rowl = wr * 64 + mi * 16 + (lane >> 4) * 4 + q;
        int grow = gr0 + rowl;
        int tok  = ptok[grow];
        if (tok >= 0) {
          float val = acc[mi][ni][q] * sc * pgate[grow];
          atomicAdd(out + (size_t)tok * DDIM + ct * 128 + coll, val);
        }
      }
  }
}

// ---------- launch ----------
extern "C" void kernel_launch(void* const* d_in, const int* in_sizes, int n_in,
                              void* d_out, int out_size, void* d_ws, size_t ws_size,
                              hipStream_t stream) {
  const float* x  = (const float*)d_in[0];
  const float* rw = (const float*)d_in[1];
  const float* wv = (const float*)d_in[2];
  const float* sv = (const float*)d_in[3];
  const float* w  = (const float*)d_in[4];
  const float* s  = (const float*)d_in[5];
  const float* w1 = (const float*)d_in[6];
  const float* s1 = (const float*)d_in[7];
  float* out = (float*)d_out;

  char* ws = (char*)d_ws;
  int*   cnt      = (int*)(ws + 0);
  int*   pofs     = (int*)(ws + 64);
  int*   meta     = (int*)(ws + 128);
  int*   tmp_tok  = (int*)(ws + 256);                       // 8*2048 ints
  float* tmp_gate = (float*)(ws + 256 + 65536);
  int*   ptok     = (int*)(ws + 256 + 131072);              // 5120 ints
  float* pgate    = (float*)(ws + 151808);
  ushort_t* Xg    = (ushort_t*)(ws + 172288);               // 5120*1024 bf16 (10MB)
  ushort_t* G     = (ushort_t*)(ws + 10658048);             // 5120*4096 bf16 (40MB)

  zero_kernel<<<2048, 256, 0, stream>>>(out, cnt);
  router_kernel<<<512, 256, 0, stream>>>(x, rw, cnt, tmp_tok, tmp_gate);
  finalize_kernel<<<1, 256, 0, stream>>>(cnt, pofs, meta, ptok, pgate, tmp_tok, tmp_gate);
  gather_kernel<<<5120, 256, 0, stream>>>(x, ptok, meta, Xg);
  gemm1_kernel<<<dim3(32, 16, 8), 256, 0, stream>>>(Xg, wv, sv, w, s, cnt, pofs, G);
  gemm2_kernel<<<dim3(8, 16, 8), 256, 0, stream>>>(G, w1, s1, cnt, pofs, ptok, pgate, out);
}

// Round 2
// 525.896 us; speedup vs baseline: 1.1063x; 1.1063x over previous
//
#include <hip/hip_runtime.h>
#include <hip/hip_bf16.h>
#include <math.h>

#define M_TOK 2048
#define DDIM  1024
#define FDIM  4096
#define NEXP  8
#define TOTROWS 5120

typedef __attribute__((ext_vector_type(8))) short short8;
typedef __attribute__((ext_vector_type(4))) float f32x4;
typedef unsigned short ushort_t;

// ---------- helpers ----------
__device__ inline unsigned short f2b(float f) {        // f32 -> bf16 RNE
  unsigned int u = __float_as_uint(f);
  u = u + 0x7FFFu + ((u >> 16) & 1u);
  return (unsigned short)(u >> 16);
}

__device__ inline float gelu_tanh(float u) {           // jax.nn.gelu approximate=True
  float u3 = u * u * u;
  float a  = 0.7978845608028654f * (u + 0.044715f * u3);
  float e  = __expf(2.0f * a);
  float t  = 1.0f - 2.0f / (e + 1.0f);                 // tanh(a), inf-safe
  return 0.5f * u * (1.0f + t);
}

__device__ inline void gload_lds16(const void* g, void* l) {
  __builtin_amdgcn_global_load_lds(
      (const __attribute__((address_space(1))) unsigned int*)g,
      (__attribute__((address_space(3))) unsigned int*)l, 16, 0, 0);
}

__device__ inline float fget(const float4& v, int j) {
  return j == 0 ? v.x : j == 1 ? v.y : j == 2 ? v.z : v.w;
}

// ---------- 0: zero out + counters ----------
__global__ void zero_kernel(float* __restrict__ out, int* __restrict__ cnt) {
  size_t i = (size_t)blockIdx.x * 256 + threadIdx.x;
  float4 z = {0.f, 0.f, 0.f, 0.f};
  ((float4*)out)[i] = z;
  if (blockIdx.x == 0 && threadIdx.x < NEXP) cnt[threadIdx.x] = 0;
}

// ---------- 1: router ----------
__global__ void router_kernel(const float* __restrict__ x, const float* __restrict__ rw,
                              int* __restrict__ cnt, int* __restrict__ tmp_tok,
                              float* __restrict__ tmp_gate) {
  int tok  = blockIdx.x * 4 + (threadIdx.x >> 6);
  int lane = threadIdx.x & 63;
  const float* xr = x + (size_t)tok * DDIM;
  double acc[NEXP];
#pragma unroll
  for (int e = 0; e < NEXP; e++) acc[e] = 0.0;
  for (int d = lane; d < DDIM; d += 64) {
    double xv = (double)xr[d];
    const float* rp = rw + (size_t)d * NEXP;
#pragma unroll
    for (int e = 0; e < NEXP; e++) acc[e] += xv * (double)rp[e];
  }
#pragma unroll
  for (int off = 32; off >= 1; off >>= 1) {
#pragma unroll
    for (int e = 0; e < NEXP; e++) acc[e] += __shfl_down(acc[e], off, 64);
  }
  if (lane == 0) {
    double mx = acc[0];
    for (int e = 1; e < NEXP; e++) mx = fmax(mx, acc[e]);
    double p[NEXP], sum = 0.0;
    for (int e = 0; e < NEXP; e++) { p[e] = exp(acc[e] - mx); sum += p[e]; }
    for (int e = 0; e < NEXP; e++) p[e] /= sum;
    int i0 = 0;
    for (int e = 1; e < NEXP; e++) if (p[e] > p[i0]) i0 = e;
    int i1 = (i0 == 0) ? 1 : 0;
    for (int e = 0; e < NEXP; e++) if (e != i0 && p[e] > p[i1]) i1 = e;
    int pos0 = atomicAdd(&cnt[i0], 1);
    tmp_tok[i0 * M_TOK + pos0]  = tok;
    tmp_gate[i0 * M_TOK + pos0] = (float)p[i0];
    int pos1 = atomicAdd(&cnt[i1], 1);
    tmp_tok[i1 * M_TOK + pos1]  = tok;
    tmp_gate[i1 * M_TOK + pos1] = (float)p[i1];
  }
}

// ---------- 2: offsets (pad to 128) + compact ----------
__global__ void finalize_kernel(const int* __restrict__ cnt, int* __restrict__ pofs,
                                int* __restrict__ meta, int* __restrict__ ptok,
                                float* __restrict__ pgate, const int* __restrict__ tmp_tok,
                                const float* __restrict__ tmp_gate) {
  __shared__ int ofs[NEXP];
  if (threadIdx.x == 0) {
    int o = 0;
    for (int e = 0; e < NEXP; e++) {
      ofs[e] = o; pofs[e] = o;
      o += ((cnt[e] + 127) >> 7) << 7;
    }
    meta[0] = o;
  }
  __syncthreads();
  for (int i = threadIdx.x; i < NEXP * M_TOK; i += 256) {
    int e = i >> 11, sl = i & 2047;
    int c = cnt[e];
    int padded = ((c + 127) >> 7) << 7;
    if (sl < padded) {
      int dst = ofs[e] + sl;
      if (sl < c) { ptok[dst] = tmp_tok[i]; pgate[dst] = tmp_gate[i]; }
      else        { ptok[dst] = -1;         pgate[dst] = 0.0f; }
    }
  }
}

// ---------- 3: gather x rows -> bf16 Xg ----------
__global__ void gather_kernel(const float* __restrict__ x, const int* __restrict__ ptok,
                              const int* __restrict__ meta, ushort_t* __restrict__ Xg) {
  int r = blockIdx.x;
  if (r >= meta[0]) return;
  int tok = ptok[r];
  int t = threadIdx.x;
  ushort4 b;
  if (tok >= 0) {
    float4 v = *(const float4*)(x + (size_t)tok * DDIM + t * 4);
    b.x = f2b(v.x); b.y = f2b(v.y); b.z = f2b(v.z); b.w = f2b(v.w);
  } else {
    b.x = 0; b.y = 0; b.z = 0; b.w = 0;
  }
  *(ushort4*)(Xg + (size_t)r * DDIM + t * 4) = b;
}

// ---------- 4: GEMM1 fused, BM=256 BN=128 BK=32, 512 thr, pipelined ----------
__launch_bounds__(512, 1)
__global__ void gemm1_kernel(const ushort_t* __restrict__ Xg,
                             const float* __restrict__ wv, const float* __restrict__ sv,
                             const float* __restrict__ w,  const float* __restrict__ s,
                             const int* __restrict__ cnt,  const int* __restrict__ pofs,
                             ushort_t* __restrict__ G) {
  int nb_tot = gridDim.x;
  int b = blockIdx.x;
  int bid = (b & 7) * (nb_tot >> 3) + (b >> 3);       // XCD chunk swizzle (T1)
  int rt = bid & 7, ct = (bid >> 3) & 31, e = bid >> 8;
  int cn = cnt[e];
  int region = ((cn + 127) >> 7) << 7;
  if (rt * 256 >= region) return;
  int gr0  = pofs[e] + rt * 256;
  int rmax = pofs[e] + region;

  __shared__ ushort_t As[2][256][32];    // 32 KB, double-buffered via global_load_lds
  __shared__ ushort_t Bs[2][128][40];    // 20 KB, [mat][n][k] padded

  int tid = threadIdx.x;
  int wid = tid >> 6, lane = tid & 63;
  int wr = wid >> 1, wc = wid & 1;       // 4M x 2N waves, 64x64 each
  int mat = tid >> 8;                    // 0: wv, 1: w
  int r8  = tid & 255;
  int kb  = r8 >> 5, nb = r8 & 31;

  const float* Bp = (mat ? w : wv) + (size_t)e * DDIM * FDIM + (size_t)ct * 128;

  f32x4 accv[4][4], accy[4][4];
  f32x4 zf = {0.f, 0.f, 0.f, 0.f};
#pragma unroll
  for (int mi = 0; mi < 4; mi++)
#pragma unroll
    for (int ni = 0; ni < 4; ni++) { accv[mi][ni] = zf; accy[mi][ni] = zf; }

  float4 q[4];
#pragma unroll
  for (int i = 0; i < 4; i++)
    q[i] = *(const float4*)(Bp + (size_t)(kb * 4 + i) * FDIM + nb * 4);
  // prologue A(0) -> buf 0
#pragma unroll
  for (int i = 0; i < 2; i++) {
    int chunk = wid * 2 + i;
    int srow = gr0 + chunk * 16 + (lane >> 2);
    if (srow > TOTROWS - 1) srow = TOTROWS - 1;
    gload_lds16(Xg + (size_t)srow * DDIM + (lane & 3) * 8, &As[0][chunk * 16][0]);
  }

  for (int kt = 0; kt < DDIM / 32; kt++) {
    int cur = kt & 1;
    // phase 1: write Bs from prefetched regs
#pragma unroll
    for (int j = 0; j < 4; j++) {
      ushort4 p;
      p.x = f2b(fget(q[0], j)); p.y = f2b(fget(q[1], j));
      p.z = f2b(fget(q[2], j)); p.w = f2b(fget(q[3], j));
      *(ushort4*)&Bs[mat][nb * 4 + j][kb * 4] = p;
    }
    __syncthreads();                      // As[cur] + Bs(kt) ready
    // phase 2: issue next-tile loads early (hide under MFMA)
    if (kt + 1 < DDIM / 32) {
#pragma unroll
      for (int i = 0; i < 2; i++) {
        int chunk = wid * 2 + i;
        int srow = gr0 + chunk * 16 + (lane >> 2);
        if (srow > TOTROWS - 1) srow = TOTROWS - 1;
        gload_lds16(Xg + (size_t)srow * DDIM + (kt + 1) * 32 + (lane & 3) * 8,
                    &As[cur ^ 1][chunk * 16][0]);
      }
#pragma unroll
      for (int i = 0; i < 4; i++)
        q[i] = *(const float4*)(Bp + (size_t)((kt + 1) * 32 + kb * 4 + i) * FDIM + nb * 4);
    }
    // phase 3: frags + MFMA
    short8 af[4], bvf[4], bwf[4];
#pragma unroll
    for (int mi = 0; mi < 4; mi++)
      af[mi] = *(const short8*)&As[cur][wr * 64 + mi * 16 + (lane & 15)][(lane >> 4) * 8];
#pragma unroll
    for (int ni = 0; ni < 4; ni++) {
      bvf[ni] = *(const short8*)&Bs[0][wc * 64 + ni * 16 + (lane & 15)][(lane >> 4) * 8];
      bwf[ni] = *(const short8*)&Bs[1][wc * 64 + ni * 16 + (lane & 15)][(lane >> 4) * 8];
    }
#pragma unroll
    for (int mi = 0; mi < 4; mi++)
#pragma unroll
      for (int ni = 0; ni < 4; ni++) {
        accv[mi][ni] = __builtin_amdgcn_mfma_f32_16x16x32_bf16(af[mi], bvf[ni], accv[mi][ni], 0, 0, 0);
        accy[mi][ni] = __builtin_amdgcn_mfma_f32_16x16x32_bf16(af[mi], bwf[ni], accy[mi][ni], 0, 0, 0);
      }
    __syncthreads();                      // readers done before next writes
  }

  const float* svp = sv + (size_t)e * FDIM + ct * 128;
  const float* sp  = s  + (size_t)e * FDIM + ct * 128;
#pragma unroll
  for (int ni = 0; ni < 4; ni++) {
    int coll = wc * 64 + ni * 16 + (lane & 15);
    float scv = svp[coll], scy = sp[coll];
#pragma unroll
    for (int mi = 0; mi < 4; mi++)
#pragma unroll
      for (int q4 = 0; q4 < 4; q4++) {
        int rowl = wr * 64 + mi * 16 + (lane >> 4) * 4 + q4;
        int grow = gr0 + rowl;
        if (grow < rmax) {
          float vv = accv[mi][ni][q4] * scv;
          float yy = accy[mi][ni][q4] * scy;
          float g  = vv * gelu_tanh(yy);
          G[(size_t)grow * FDIM + ct * 128 + coll] = f2b(g);
        }
      }
  }
}

// ---------- 5: GEMM2 K-split x2, BM=128 BN=128, pipelined ----------
__launch_bounds__(256, 2)
__global__ void gemm2_kernel(const ushort_t* __restrict__ G,
                             const float* __restrict__ w1, const float* __restrict__ s1,
                             const int* __restrict__ cnt,  const int* __restrict__ pofs,
                             const int* __restrict__ ptok, const float* __restrict__ pgate,
                             float* __restrict__ out) {
  int nb_tot = gridDim.x;
  int b = blockIdx.x;
  int bid = (b & 7) * (nb_tot >> 3) + (b >> 3);       // XCD chunk swizzle
  int rt = bid & 15, ct = (bid >> 4) & 7, ks = (bid >> 7) & 1, e = bid >> 8;
  int cn = cnt[e];
  int region = ((cn + 127) >> 7) << 7;
  if (rt * 128 >= region) return;
  int gr0 = pofs[e] + rt * 128;
  int k0  = ks * 2048;

  const float* Bp = w1 + (size_t)e * FDIM * DDIM + (size_t)ct * 128;

  __shared__ ushort_t As[2][128][32];    // 16 KB
  __shared__ ushort_t Bs[128][40];       // 10 KB

  int tid = threadIdx.x;
  int wid = tid >> 6, lane = tid & 63;
  int wr = wid >> 1, wc = wid & 1;
  int kb = tid >> 5, nb = tid & 31;

  f32x4 acc[4][4];
  f32x4 zf = {0.f, 0.f, 0.f, 0.f};
#pragma unroll
  for (int mi = 0; mi < 4; mi++)
#pragma unroll
    for (int ni = 0; ni < 4; ni++) acc[mi][ni] = zf;

  float4 q[4];
#pragma unroll
  for (int i = 0; i < 4; i++)
    q[i] = *(const float4*)(Bp + (size_t)(k0 + kb * 4 + i) * DDIM + nb * 4);
#pragma unroll
  for (int i = 0; i < 2; i++) {
    int chunk = wid * 2 + i;
    gload_lds16(G + (size_t)(gr0 + chunk * 16 + (lane >> 2)) * FDIM + k0 + (lane & 3) * 8,
                &As[0][chunk * 16][0]);
  }

  for (int kt = 0; kt < 64; kt++) {
    int cur = kt & 1;
#pragma unroll
    for (int j = 0; j < 4; j++) {
      ushort4 p;
      p.x = f2b(fget(q[0], j)); p.y = f2b(fget(q[1], j));
      p.z = f2b(fget(q[2], j)); p.w = f2b(fget(q[3], j));
      *(ushort4*)&Bs[nb * 4 + j][kb * 4] = p;
    }
    __syncthreads();
    if (kt + 1 < 64) {
#pragma unroll
      for (int i = 0; i < 2; i++) {
        int chunk = wid * 2 + i;
        gload_lds16(G + (size_t)(gr0 + chunk * 16 + (lane >> 2)) * FDIM + k0 + (kt + 1) * 32 + (lane & 3) * 8,
                    &As[cur ^ 1][chunk * 16][0]);
      }
#pragma unroll
      for (int i = 0; i < 4; i++)
        q[i] = *(const float4*)(Bp + (size_t)(k0 + (kt + 1) * 32 + kb * 4 + i) * DDIM + nb * 4);
    }
    short8 af[4], bf[4];
#pragma unroll
    for (int mi = 0; mi < 4; mi++)
      af[mi] = *(const short8*)&As[cur][wr * 64 + mi * 16 + (lane & 15)][(lane >> 4) * 8];
#pragma unroll
    for (int ni = 0; ni < 4; ni++)
      bf[ni] = *(const short8*)&Bs[wc * 64 + ni * 16 + (lane & 15)][(lane >> 4) * 8];
#pragma unroll
    for (int mi = 0; mi < 4; mi++)
#pragma unroll
      for (int ni = 0; ni < 4; ni++)
        acc[mi][ni] = __builtin_amdgcn_mfma_f32_16x16x32_bf16(af[mi], bf[ni], acc[mi][ni], 0, 0, 0);
    __syncthreads();
  }

  const float* s1p = s1 + (size_t)e * DDIM + ct * 128;
#pragma unroll
  for (int ni = 0; ni < 4; ni++) {
    int coll = wc * 64 + ni * 16 + (lane & 15);
    float sc = s1p[coll];
#pragma unroll
    for (int mi = 0; mi < 4; mi++)
#pragma unroll
      for (int q4 = 0; q4 < 4; q4++) {
        int rowl = wr * 64 + mi * 16 + (lane >> 4) * 4 + q4;
        int grow = gr0 + rowl;
        int tok  = ptok[grow];
        if (tok >= 0) {
          float val = acc[mi][ni][q4] * sc * pgate[grow];
          atomicAdd(out + (size_t)tok * DDIM + ct * 128 + coll, val);
        }
      }
  }
}

// ---------- launch ----------
extern "C" void kernel_launch(void* const* d_in, const int* in_sizes, int n_in,
                              void* d_out, int out_size, void* d_ws, size_t ws_size,
                              hipStream_t stream) {
  const float* x  = (const float*)d_in[0];
  const float* rw = (const float*)d_in[1];
  const float* wv = (const float*)d_in[2];
  const float* sv = (const float*)d_in[3];
  const float* w  = (const float*)d_in[4];
  const float* s  = (const float*)d_in[5];
  const float* w1 = (const float*)d_in[6];
  const float* s1 = (const float*)d_in[7];
  float* out = (float*)d_out;

  char* ws = (char*)d_ws;
  int*   cnt      = (int*)(ws + 0);
  int*   pofs     = (int*)(ws + 64);
  int*   meta     = (int*)(ws + 128);
  int*   tmp_tok  = (int*)(ws + 256);
  float* tmp_gate = (float*)(ws + 256 + 65536);
  int*   ptok     = (int*)(ws + 256 + 131072);
  float* pgate    = (float*)(ws + 151808);
  ushort_t* Xg    = (ushort_t*)(ws + 172288);
  ushort_t* G     = (ushort_t*)(ws + 10658048);

  zero_kernel<<<2048, 256, 0, stream>>>(out, cnt);
  router_kernel<<<512, 256, 0, stream>>>(x, rw, cnt, tmp_tok, tmp_gate);
  finalize_kernel<<<1, 256, 0, stream>>>(cnt, pofs, meta, ptok, pgate, tmp_tok, tmp_gate);
  gather_kernel<<<5120, 256, 0, stream>>>(x, ptok, meta, Xg);
  gemm1_kernel<<<2048, 512, 0, stream>>>(Xg, wv, sv, w, s, cnt, pofs, G);
  gemm2_kernel<<<2048, 256, 0, stream>>>(G, w1, s1, cnt, pofs, ptok, pgate, out);
}

// Round 3
// 429.034 us; speedup vs baseline: 1.3560x; 1.2258x over previous
//
#include <hip/hip_runtime.h>
#include <hip/hip_bf16.h>
#include <math.h>

#define M_TOK 2048
#define DDIM  1024
#define FDIM  4096
#define NEXP  8
#define TOTROWS 5120
#define NTMAX 40

typedef __attribute__((ext_vector_type(8))) short short8;
typedef __attribute__((ext_vector_type(4))) short short4v;
typedef __attribute__((ext_vector_type(4))) float f32x4;
typedef unsigned short ushort_t;

// ---------- helpers ----------
__device__ inline unsigned short f2b(float f) {        // f32 -> bf16 RNE
  unsigned int u = __float_as_uint(f);
  u = u + 0x7FFFu + ((u >> 16) & 1u);
  return (unsigned short)(u >> 16);
}

__device__ inline float gelu_tanh(float u) {           // jax.nn.gelu approximate=True
  float u3 = u * u * u;
  float a  = 0.7978845608028654f * (u + 0.044715f * u3);
  float e  = __expf(2.0f * a);
  float t  = 1.0f - 2.0f / (e + 1.0f);                 // tanh(a), inf-safe
  return 0.5f * u * (1.0f + t);
}

__device__ inline void gload_lds16(const void* g, void* l) {
  __builtin_amdgcn_global_load_lds(
      (const __attribute__((address_space(1))) unsigned int*)g,
      (__attribute__((address_space(3))) unsigned int*)l, 16, 0, 0);
}

// ---------- 0: zero out + counters ----------
__global__ void zero_kernel(float* __restrict__ out, int* __restrict__ cnt) {
  size_t i = (size_t)blockIdx.x * 256 + threadIdx.x;
  float4 z = {0.f, 0.f, 0.f, 0.f};
  ((float4*)out)[i] = z;
  if (blockIdx.x == 0 && threadIdx.x < NEXP) cnt[threadIdx.x] = 0;
}

// ---------- 1: router ----------
__global__ void router_kernel(const float* __restrict__ x, const float* __restrict__ rw,
                              int* __restrict__ cnt, int* __restrict__ tmp_tok,
                              float* __restrict__ tmp_gate) {
  int tok  = blockIdx.x * 4 + (threadIdx.x >> 6);
  int lane = threadIdx.x & 63;
  const float* xr = x + (size_t)tok * DDIM;
  double acc[NEXP];
#pragma unroll
  for (int e = 0; e < NEXP; e++) acc[e] = 0.0;
  for (int d = lane; d < DDIM; d += 64) {
    double xv = (double)xr[d];
    const float* rp = rw + (size_t)d * NEXP;
#pragma unroll
    for (int e = 0; e < NEXP; e++) acc[e] += xv * (double)rp[e];
  }
#pragma unroll
  for (int off = 32; off >= 1; off >>= 1) {
#pragma unroll
    for (int e = 0; e < NEXP; e++) acc[e] += __shfl_down(acc[e], off, 64);
  }
  if (lane == 0) {
    double mx = acc[0];
    for (int e = 1; e < NEXP; e++) mx = fmax(mx, acc[e]);
    double p[NEXP], sum = 0.0;
    for (int e = 0; e < NEXP; e++) { p[e] = exp(acc[e] - mx); sum += p[e]; }
    for (int e = 0; e < NEXP; e++) p[e] /= sum;
    int i0 = 0;
    for (int e = 1; e < NEXP; e++) if (p[e] > p[i0]) i0 = e;
    int i1 = (i0 == 0) ? 1 : 0;
    for (int e = 0; e < NEXP; e++) if (e != i0 && p[e] > p[i1]) i1 = e;
    int pos0 = atomicAdd(&cnt[i0], 1);
    tmp_tok[i0 * M_TOK + pos0]  = tok;
    tmp_gate[i0 * M_TOK + pos0] = (float)p[i0];
    int pos1 = atomicAdd(&cnt[i1], 1);
    tmp_tok[i1 * M_TOK + pos1]  = tok;
    tmp_gate[i1 * M_TOK + pos1] = (float)p[i1];
  }
}

// ---------- 2: offsets (pad to 128), tile list, compact ----------
__global__ void finalize_kernel(const int* __restrict__ cnt, int* __restrict__ pofs,
                                int* __restrict__ meta, int* __restrict__ tle,
                                int* __restrict__ tlr, int* __restrict__ ptok,
                                float* __restrict__ pgate, const int* __restrict__ tmp_tok,
                                const float* __restrict__ tmp_gate) {
  __shared__ int ofs[NEXP];
  if (threadIdx.x == 0) {
    int o = 0, t = 0;
    for (int e = 0; e < NEXP; e++) {
      ofs[e] = o; pofs[e] = o;
      int nt = (cnt[e] + 127) >> 7;
      for (int i = 0; i < nt; i++) { tle[t] = e; tlr[t] = o + i * 128; t++; }
      o += nt << 7;
    }
    meta[0] = o; meta[1] = t;
  }
  __syncthreads();
  for (int i = threadIdx.x; i < NEXP * M_TOK; i += 256) {
    int e = i >> 11, sl = i & 2047;
    int c = cnt[e];
    int padded = ((c + 127) >> 7) << 7;
    if (sl < padded) {
      int dst = ofs[e] + sl;
      if (sl < c) { ptok[dst] = tmp_tok[i]; pgate[dst] = tmp_gate[i]; }
      else        { ptok[dst] = -1;         pgate[dst] = 0.0f; }
    }
  }
}

// ---------- 3: gather x rows -> bf16 Xg ----------
__global__ void gather_kernel(const float* __restrict__ x, const int* __restrict__ ptok,
                              const int* __restrict__ meta, ushort_t* __restrict__ Xg) {
  int r = blockIdx.x;
  if (r >= meta[0]) return;
  int tok = ptok[r];
  int t = threadIdx.x;
  ushort4 b;
  if (tok >= 0) {
    float4 v = *(const float4*)(x + (size_t)tok * DDIM + t * 4);
    b.x = f2b(v.x); b.y = f2b(v.y); b.z = f2b(v.z); b.w = f2b(v.w);
  } else {
    b.x = 0; b.y = 0; b.z = 0; b.w = 0;
  }
  *(ushort4*)(Xg + (size_t)r * DDIM + t * 4) = b;
}

// ---------- 3b: convert+transpose+fold-scale: src[e][K][N] f32 -> dst[e][N][K] bf16 ----------
// dst[e][n][k] = bf16(src[e][k][n] * scale[e][n]).  64x64 tiles via LDS.
__global__ void convert_kernel(const float* __restrict__ src, const float* __restrict__ scale,
                               ushort_t* __restrict__ dst, int K, int N) {
  int e = blockIdx.y;
  int ntn = N >> 6;
  int tk = blockIdx.x / ntn;
  int tn = blockIdx.x - tk * ntn;
  const float* S = src + (size_t)e * K * N;
  ushort_t* D = dst + (size_t)e * N * K;
  const float* sc = scale + (size_t)e * N;
  __shared__ ushort_t lds[64][68];       // pad 68: 136B rows (8B-aligned, conflict-spread)
  int t = threadIdx.x;
  int kl = t >> 4;                       // 0..15
  int nl = (t & 15) * 4;
  int k0 = tk * 64, n0 = tn * 64;
  float4 scv = *(const float4*)(sc + n0 + nl);
#pragma unroll
  for (int i = 0; i < 4; i++) {
    int k = kl + i * 16;
    float4 v = *(const float4*)(S + (size_t)(k0 + k) * N + n0 + nl);
    lds[nl + 0][k] = f2b(v.x * scv.x);
    lds[nl + 1][k] = f2b(v.y * scv.y);
    lds[nl + 2][k] = f2b(v.z * scv.z);
    lds[nl + 3][k] = f2b(v.w * scv.w);
  }
  __syncthreads();
  int nr = t >> 3;                       // 0..31
  int kc = (t & 7) * 8;
#pragma unroll
  for (int i = 0; i < 2; i++) {
    int n = nr + i * 32;
    short4v lo = *(const short4v*)&lds[n][kc];
    short4v hi = *(const short4v*)&lds[n][kc + 4];
    short8 v8;
    v8[0]=lo[0]; v8[1]=lo[1]; v8[2]=lo[2]; v8[3]=lo[3];
    v8[4]=hi[0]; v8[5]=hi[1]; v8[6]=hi[2]; v8[7]=hi[3];
    *(short8*)(D + (size_t)(n0 + n) * K + k0 + kc) = v8;
  }
}

// ---------- 4: GEMM1 fused (m97 structure): G = (Xg@WvT) * gelu(Xg@WT) ----------
__launch_bounds__(256, 2)
__global__ void gemm1_kernel(const ushort_t* __restrict__ Xg,
                             const ushort_t* __restrict__ WvT, const ushort_t* __restrict__ WT,
                             const int* __restrict__ tle, const int* __restrict__ tlr,
                             const int* __restrict__ meta, ushort_t* __restrict__ G) {
  int b = blockIdx.x;                              // 1280 = 8*160
  int bid = (b & 7) * 160 + (b >> 3);              // bijective XCD chunk swizzle
  int ct = bid / NTMAX;
  int t  = bid - ct * NTMAX;
  if (t >= meta[1]) return;
  int e = tle[t], gr0 = tlr[t];

  __shared__ ushort_t As[128][32];
  __shared__ ushort_t Bv[128][32];
  __shared__ ushort_t Bw[128][32];

  int tid = threadIdx.x, wid = tid >> 6, lane = tid & 63;
  int wr = wid >> 1, wc = wid & 1;
  int srow = wid * 32 + (lane >> 2);
  int scol = (lane & 3) * 8;

  const ushort_t* Ap  = Xg  + (size_t)(gr0 + srow) * DDIM + scol;
  const ushort_t* Bvp = WvT + ((size_t)e * FDIM + ct * 128 + srow) * DDIM + scol;
  const ushort_t* Bwp = WT  + ((size_t)e * FDIM + ct * 128 + srow) * DDIM + scol;

  f32x4 accv[4][4], accy[4][4];
  f32x4 zf = {0.f, 0.f, 0.f, 0.f};
#pragma unroll
  for (int mi = 0; mi < 4; mi++)
#pragma unroll
    for (int ni = 0; ni < 4; ni++) { accv[mi][ni] = zf; accy[mi][ni] = zf; }

  for (int kt = 0; kt < DDIM / 32; kt++) {
    __syncthreads();
    gload_lds16(Ap  + kt * 32,             &As[wid * 32][0]);
    gload_lds16(Ap  + kt * 32 + 16 * DDIM, &As[wid * 32 + 16][0]);
    gload_lds16(Bvp + kt * 32,             &Bv[wid * 32][0]);
    gload_lds16(Bvp + kt * 32 + 16 * DDIM, &Bv[wid * 32 + 16][0]);
    gload_lds16(Bwp + kt * 32,             &Bw[wid * 32][0]);
    gload_lds16(Bwp + kt * 32 + 16 * DDIM, &Bw[wid * 32 + 16][0]);
    __syncthreads();

    short8 af[4], bvf[4], bwf[4];
#pragma unroll
    for (int mi = 0; mi < 4; mi++)
      af[mi] = *(const short8*)&As[wr * 64 + mi * 16 + (lane & 15)][(lane >> 4) * 8];
#pragma unroll
    for (int ni = 0; ni < 4; ni++) {
      bvf[ni] = *(const short8*)&Bv[wc * 64 + ni * 16 + (lane & 15)][(lane >> 4) * 8];
      bwf[ni] = *(const short8*)&Bw[wc * 64 + ni * 16 + (lane & 15)][(lane >> 4) * 8];
    }
#pragma unroll
    for (int mi = 0; mi < 4; mi++)
#pragma unroll
      for (int ni = 0; ni < 4; ni++) {
        accv[mi][ni] = __builtin_amdgcn_mfma_f32_16x16x32_bf16(af[mi], bvf[ni], accv[mi][ni], 0, 0, 0);
        accy[mi][ni] = __builtin_amdgcn_mfma_f32_16x16x32_bf16(af[mi], bwf[ni], accy[mi][ni], 0, 0, 0);
      }
  }

#pragma unroll
  for (int ni = 0; ni < 4; ni++) {
    int coll = wc * 64 + ni * 16 + (lane & 15);
#pragma unroll
    for (int mi = 0; mi < 4; mi++)
#pragma unroll
      for (int q = 0; q < 4; q++) {
        int rowl = wr * 64 + mi * 16 + (lane >> 4) * 4 + q;
        float g = accv[mi][ni][q] * gelu_tanh(accy[mi][ni][q]);
        G[(size_t)(gr0 + rowl) * FDIM + ct * 128 + coll] = f2b(g);
      }
  }
}

// ---------- 5: GEMM2 (m97 structure, K-split x2): out[tok] += gate*(G@W1T) ----------
__launch_bounds__(256, 3)
__global__ void gemm2_kernel(const ushort_t* __restrict__ G,
                             const ushort_t* __restrict__ W1T,
                             const int* __restrict__ tle, const int* __restrict__ tlr,
                             const int* __restrict__ meta, const int* __restrict__ ptok,
                             const float* __restrict__ pgate, float* __restrict__ out) {
  int b = blockIdx.x;                              // 640 = 8*80
  int bid = (b & 7) * 80 + (b >> 3);
  int grp = bid / NTMAX;                           // 0..15 = ct*2+ks
  int t = bid - grp * NTMAX;
  if (t >= meta[1]) return;
  int ct = grp >> 1, ks = grp & 1;
  int e = tle[t], gr0 = tlr[t];
  int k0 = ks * (FDIM / 2);

  __shared__ ushort_t As[128][32];
  __shared__ ushort_t Bs[128][32];

  int tid = threadIdx.x, wid = tid >> 6, lane = tid & 63;
  int wr = wid >> 1, wc = wid & 1;
  int srow = wid * 32 + (lane >> 2);
  int scol = (lane & 3) * 8;

  const ushort_t* Ap = G   + (size_t)(gr0 + srow) * FDIM + k0 + scol;
  const ushort_t* Bp = W1T + ((size_t)e * DDIM + ct * 128 + srow) * FDIM + k0 + scol;

  f32x4 acc[4][4];
  f32x4 zf = {0.f, 0.f, 0.f, 0.f};
#pragma unroll
  for (int mi = 0; mi < 4; mi++)
#pragma unroll
    for (int ni = 0; ni < 4; ni++) acc[mi][ni] = zf;

  for (int kt = 0; kt < (FDIM / 2) / 32; kt++) {
    __syncthreads();
    gload_lds16(Ap + kt * 32,             &As[wid * 32][0]);
    gload_lds16(Ap + kt * 32 + 16 * FDIM, &As[wid * 32 + 16][0]);
    gload_lds16(Bp + kt * 32,             &Bs[wid * 32][0]);
    gload_lds16(Bp + kt * 32 + 16 * FDIM, &Bs[wid * 32 + 16][0]);
    __syncthreads();

    short8 af[4], bf[4];
#pragma unroll
    for (int mi = 0; mi < 4; mi++)
      af[mi] = *(const short8*)&As[wr * 64 + mi * 16 + (lane & 15)][(lane >> 4) * 8];
#pragma unroll
    for (int ni = 0; ni < 4; ni++)
      bf[ni] = *(const short8*)&Bs[wc * 64 + ni * 16 + (lane & 15)][(lane >> 4) * 8];
#pragma unroll
    for (int mi = 0; mi < 4; mi++)
#pragma unroll
      for (int ni = 0; ni < 4; ni++)
        acc[mi][ni] = __builtin_amdgcn_mfma_f32_16x16x32_bf16(af[mi], bf[ni], acc[mi][ni], 0, 0, 0);
  }

#pragma unroll
  for (int ni = 0; ni < 4; ni++) {
    int coll = wc * 64 + ni * 16 + (lane & 15);
#pragma unroll
    for (int mi = 0; mi < 4; mi++)
#pragma unroll
      for (int q = 0; q < 4; q++) {
        int rowl = wr * 64 + mi * 16 + (lane >> 4) * 4 + q;
        int grow = gr0 + rowl;
        int tok  = ptok[grow];
        if (tok >= 0) {
          float val = acc[mi][ni][q] * pgate[grow];
          atomicAdd(out + (size_t)tok * DDIM + ct * 128 + coll, val);
        }
      }
  }
}

// ---------- launch ----------
extern "C" void kernel_launch(void* const* d_in, const int* in_sizes, int n_in,
                              void* d_out, int out_size, void* d_ws, size_t ws_size,
                              hipStream_t stream) {
  const float* x  = (const float*)d_in[0];
  const float* rw = (const float*)d_in[1];
  const float* wv = (const float*)d_in[2];
  const float* sv = (const float*)d_in[3];
  const float* w  = (const float*)d_in[4];
  const float* s  = (const float*)d_in[5];
  const float* w1 = (const float*)d_in[6];
  const float* s1 = (const float*)d_in[7];
  float* out = (float*)d_out;

  char* ws = (char*)d_ws;
  int*   cnt      = (int*)(ws + 0);
  int*   pofs     = (int*)(ws + 64);
  int*   meta     = (int*)(ws + 128);
  int*   tle      = (int*)(ws + 192);
  int*   tlr      = (int*)(ws + 512);
  int*   tmp_tok  = (int*)(ws + 1024);
  float* tmp_gate = (float*)(ws + 66560);
  int*   ptok     = (int*)(ws + 132096);
  float* pgate    = (float*)(ws + 152576);
  ushort_t* Xg    = (ushort_t*)(ws + 173056);      // 10 MB
  ushort_t* G     = (ushort_t*)(ws + 10658816);    // 40 MB
  ushort_t* WvT   = (ushort_t*)(ws + 52601856);    // 64 MB
  ushort_t* WT    = (ushort_t*)(ws + 119710720);   // 64 MB
  ushort_t* W1T   = (ushort_t*)(ws + 186819584);   // 64 MB (end ~242 MB)

  zero_kernel<<<2048, 256, 0, stream>>>(out, cnt);
  router_kernel<<<512, 256, 0, stream>>>(x, rw, cnt, tmp_tok, tmp_gate);
  finalize_kernel<<<1, 256, 0, stream>>>(cnt, pofs, meta, tle, tlr, ptok, pgate, tmp_tok, tmp_gate);
  gather_kernel<<<5120, 256, 0, stream>>>(x, ptok, meta, Xg);
  convert_kernel<<<dim3(1024, 8), 256, 0, stream>>>(wv, sv, WvT, DDIM, FDIM);
  convert_kernel<<<dim3(1024, 8), 256, 0, stream>>>(w,  s,  WT,  DDIM, FDIM);
  convert_kernel<<<dim3(1024, 8), 256, 0, stream>>>(w1, s1, W1T, FDIM, DDIM);
  gemm1_kernel<<<1280, 256, 0, stream>>>(Xg, WvT, WT, tle, tlr, meta, G);
  gemm2_kernel<<<640, 256, 0, stream>>>(G, W1T, tle, tlr, meta, ptok, pgate, out);
}